// Round 3
// baseline (112.008 us; speedup 1.0000x reference)
//
#include <hip/hip_runtime.h>

// SpikeAmplifier: T=128, N=16, C=1, J=8192.
// Per-element (n,c,j) serial recurrence over t:
//   h = y*h + w*y;  x = x_t + h;  v = v + x;
//   s = (v >= 1);  v = s ? 0 : v;  out[t] = s;  y = s
// Pure streaming, memory-bound: 64 MiB in + 64 MiB out. Kernel floor ~21 us
// @ 6.3 TB/s. R5 (float2, full unroll, no nt) reached ~28 us (~4.8 TB/s).
//
// R6 change vs R5: access WIDTH. float4 per thread (dwordx4, 1 KiB/wave-instr)
// — the m13 6.29 TB/s copy recipe width — instead of float2 (512 B/wave-instr).
// Halves VMEM instruction count per byte; bigger per-request bursts.
// Grid: 32768 float4 columns = 512 blocks x 64 threads = 2 waves/CU; in-flight
// bytes/CU unchanged (2 waves x 16 slots x 1 KiB = 32 KiB). Keeps R5's proven
// structure: plain (non-nt) loads/stores, fully-unrolled straight-line t-loop
// (no back-edge -> exact counted vmcnt waits), rolling prefetch depth U=16.
// I$ footprint ~27 KiB < 32 KiB. Per-element arithmetic order unchanged
// (bit-exact: y in {0,1} makes h = y*h + w*y exact under FMA contraction).

#define T_STEPS 128
#define J_DIM   8192
#define NCJ     131072            // N*C*J — per-timestep element count (floats)
#define NCJ4    (NCJ / 4)         // per-timestep stride in float4 units (32768)
#define U       16                // rolling prefetch distance (t-steps)

typedef float v4f __attribute__((ext_vector_type(4)));

__global__ __launch_bounds__(64) void SpikeAmplifier_73452530696745_kernel(
    const float* __restrict__ in,    // (T, N, C, J) fp32
    const float* __restrict__ w,     // (J,) fp32
    float* __restrict__ out)         // (T, N, C, J) fp32 spikes
{
    const int idx4 = blockIdx.x * blockDim.x + threadIdx.x;  // 0 .. NCJ4-1
    const int jbase = (idx4 * 4) & (J_DIM - 1);
    const v4f wv = *(const v4f*)&w[jbase];

    const v4f* __restrict__ in4  = (const v4f*)in + idx4;
    v4f* __restrict__       out4 = (v4f*)out + idx4;

    v4f h = {0.f, 0.f, 0.f, 0.f};
    v4f y = {0.f, 0.f, 0.f, 0.f};
    v4f v = {0.f, 0.f, 0.f, 0.f};

    // Fill the 16-deep rolling buffer with t = 0..U-1.
    v4f xbuf[U];
    #pragma unroll
    for (int u = 0; u < U; ++u)
        xbuf[u] = in4[(size_t)u * NCJ4];

    // Straight-line main body: every index is a compile-time constant after
    // unrolling; each step consumes slot (t mod U) and refills it with t+U.
    #pragma unroll
    for (int t = 0; t < T_STEPS; ++t) {
        const v4f xt = xbuf[t & (U - 1)];
        if (t + U < T_STEPS)                       // constant-folds per step
            xbuf[t & (U - 1)] = in4[(size_t)(t + U) * NCJ4];

        v4f yv;
        #pragma unroll
        for (int e = 0; e < 4; ++e) {
            h[e] = y[e] * h[e] + wv[e] * y[e];
            const float x = xt[e] + h[e];
            v[e] = v[e] + x;
            const bool s = (v[e] >= 1.0f);
            y[e] = s ? 1.0f : 0.0f;
            v[e] = s ? 0.0f : v[e];
            yv[e] = y[e];
        }
        out4[(size_t)t * NCJ4] = yv;
    }
}

extern "C" void kernel_launch(void* const* d_in, const int* in_sizes, int n_in,
                              void* d_out, int out_size, void* d_ws, size_t ws_size,
                              hipStream_t stream) {
    const float* in  = (const float*)d_in[0];   // (T,N,C,J) = 16,777,216 floats
    const float* w   = (const float*)d_in[1];   // (J,) = 8192 floats
    float*       out = (float*)d_out;           // (T,N,C,J)

    // 32768 threads = 512 blocks x 64 = 2 single-wave blocks per CU.
    SpikeAmplifier_73452530696745_kernel<<<NCJ4 / 64, 64, 0, stream>>>(in, w, out);
}